// Round 7
// baseline (149.342 us; speedup 1.0000x reference)
//
#include <hip/hip_runtime.h>

// EulerIntegrator: B=4096, D=1024, R=256, steps=8, dt=0.01
// R7: (1) WU B-fragments live in registers (each wave only reads its own
//     nt=wave column) -- kills ~1MB/CU/step-loop LDS reads + wu8 staging;
//     (2) epilogue terms e1=x0+s*dt*v0+T*dt^2*f, e2=v0+s*dt*f folded into
//     registers during staging -- epilogue does ZERO global reads and x0's
//     HBM read overlaps all compute; (3) pack WU vectorized: wave-uniform W
//     scalar x float4 U lines, 64-load chains (was 1024).
// Recurrence: P <- P + dt*(FU - (P*P)@WU) in [B,256];
//   v_fin = e2 - dt*(Q1@W),  x_fin = e1 - dt^2*(Q2@W)

#define BB 4096
#define DD 1024
#define RR 256
#define DT 0.01f

typedef __attribute__((ext_vector_type(8))) short short8;   // 8 bf16 = 4 VGPRs
typedef __attribute__((ext_vector_type(4))) short short4v;  // 4 bf16 = 8B
typedef __attribute__((ext_vector_type(4))) float floatx4;  // MFMA acc

static __device__ inline unsigned short f2bf(float f) {
    union { float f; unsigned int u; } c; c.f = f;
    unsigned int u = c.u;
    u += 0x7fffu + ((u >> 16) & 1u);   // round-to-nearest-even
    return (unsigned short)(u >> 16);
}

// Fragment layout (B-operand, 16x16x32): frag (kt,nt), lane l, elem j holds
// M[kt*32 + (l>>4)*8 + j][nt*16 + (l&15)]; short index = frag*512 + l*8 + j.
//
// Blocks 0..63:    pack U  (32 kt x 16 nt)
// Blocks 64..127:  pack W  ( 8 kt x 64 nt)
// Blocks 128..383: WU row i = b-128; 16 k-slices x 64 float4-cols,
//                  wave-uniform W scalar, coalesced float4 U, LDS reduce.
__global__ __launch_bounds__(1024)
void pack_kernel(const float* __restrict__ U, const float* __restrict__ W,
                 short* __restrict__ Up, short* __restrict__ Wp,
                 short* __restrict__ WUp) {
    __shared__ float4 red[16][64];   // 16 KB, WU blocks only
    const int b = blockIdx.x;
    const int tid = threadIdx.x;

    if (b < 128) {
        const bool isU = (b < 64);
        const float* M = isU ? U : W;
        short* P = isU ? Up : Wp;
        const int ld = isU ? RR : DD;
        int t = (isU ? b : b - 64) * 1024 + tid;   // 0..65535
        int S = t * 4;                              // short index of first elem
        int j0   = S & 7;                           // 0 or 4
        int lane = (S >> 3) & 63;
        int frag = S >> 9;                          // kt*NT + nt
        int nl = lane & 15, kq = lane >> 4;
        int kt, nt;
        if (isU) { kt = frag >> 4; nt = frag & 15; }
        else     { kt = frag >> 6; nt = frag & 63; }
        int k0 = kt * 32 + kq * 8 + j0;
        int n  = nt * 16 + nl;
        short4v o;
#pragma unroll
        for (int jj = 0; jj < 4; jj++)
            o[jj] = (short)f2bf(M[(long)(k0 + jj) * ld + n]);
        *(short4v*)(P + S) = o;                     // coalesced 8B write
    } else {
        // WU[i][j] = sum_k W[i][k]*U[k][j]; i = b-128.
        // thread (ks = tid>>6, j4 = tid&63): wave = one k-slice of 64.
        const int i  = b - 128;
        const int ks = tid >> 6;                    // 0..15
        const int j4 = tid & 63;
        const float4* U4 = (const float4*)U;
        const float*  wr = W + (long)i * DD + ks * 64;
        float4 acc = {0.f, 0.f, 0.f, 0.f};
#pragma unroll 8
        for (int m = 0; m < 64; m++) {
            float w = wr[m];                        // wave-uniform
            float4 u = U4[(ks * 64 + m) * 64 + j4]; // 1KB/wave coalesced
            acc.x += w * u.x; acc.y += w * u.y;
            acc.z += w * u.z; acc.w += w * u.w;
        }
        red[ks][j4] = acc;
        __syncthreads();
        if (tid < 64) {
            float4 a = red[0][tid];
#pragma unroll
            for (int s = 1; s < 16; s++) {
                float4 r = red[s][tid];
                a.x += r.x; a.y += r.y; a.z += r.z; a.w += r.w;
            }
            int ktw = i >> 5, kqw = (i >> 3) & 3, jjw = i & 7;
            float av[4] = {a.x, a.y, a.z, a.w};
#pragma unroll
            for (int c = 0; c < 4; c++) {
                int j = 4 * tid + c;
                int nt = j >> 4, nl = j & 15;
                WUp[(((ktw * 16 + nt) * 64) + kqw * 16 + nl) * 8 + jjw] =
                    (short)f2bf(av[c]);
            }
        }
    }
}

__global__ __launch_bounds__(1024)
void euler_kernel(const float* __restrict__ x0,
                  const float* __restrict__ v0,
                  const float* __restrict__ force,
                  const short8* __restrict__ Up,
                  const short8* __restrict__ Wp,
                  const short8* __restrict__ WUp,
                  const int* __restrict__ steps_p,
                  float* __restrict__ out) {
    // LDS layout (shorts), 74240 shorts = 148,480 B (1 block/CU):
    //   [0     .. 16511]  va [16][1032] bf16 v0     } epilogue: s1 f32
    //   [16512 .. 33023]  fa [16][1032] bf16 f      } [16][1024] aliases both
    //   [33024 .. 37247]  q1 [16][264]  (step dbuf / final Q1)
    //   [37248 .. 41471]  q2 [16][264]  (step dbuf / final Q2)
    //   [41472 .. 74239]  s2 f32 [16][1024] (epilogue only)
    __shared__ __align__(16) short smem[74240];

    const int tid  = threadIdx.x;
    const int wave = tid >> 6;          // 0..15
    const int lane = tid & 63;
    const int nl   = lane & 15;
    const int quad = lane >> 4;
    const int row0 = blockIdx.x * 16;
    const int steps = steps_p[0];
    const float sdt  = steps * DT;
    const float tdt2 = 0.5f * (float)(steps * (steps - 1)) * DT * DT;

    short (*va)[1032] = (short(*)[1032])smem;
    short (*fa)[1032] = (short(*)[1032])(smem + 16512);
    short (*q1)[264]  = (short(*)[264])(smem + 33024);
    short (*q2)[264]  = (short(*)[264])(smem + 37248);

    // ---- stage v0, f as bf16; fold x0/v0/f into epilogue terms in regs:
    //   e1 = x0 + s*dt*v0 + T*dt^2*f,  e2 = v0 + s*dt*f
    const float4* v04 = (const float4*)v0;
    const float4* f44 = (const float4*)force;
    const float4* x4  = (const float4*)x0;
    float4 e1[4], e2[4];
#pragma unroll
    for (int i = 0; i < 4; i++) {
        int idx = tid + i * 1024;       // 0..4095
        int row = idx >> 8, c4 = idx & 255;
        long g = (long)(row0 + row) * 256 + c4;
        float4 vv = v04[g];
        float4 ff = f44[g];
        float4 xx = x4[g];
        short4v sv, sf;
        sv[0] = (short)f2bf(vv.x); sv[1] = (short)f2bf(vv.y);
        sv[2] = (short)f2bf(vv.z); sv[3] = (short)f2bf(vv.w);
        sf[0] = (short)f2bf(ff.x); sf[1] = (short)f2bf(ff.y);
        sf[2] = (short)f2bf(ff.z); sf[3] = (short)f2bf(ff.w);
        *(short4v*)&va[row][c4 * 4] = sv;
        *(short4v*)&fa[row][c4 * 4] = sf;
        e1[i].x = xx.x + sdt * vv.x + tdt2 * ff.x;
        e1[i].y = xx.y + sdt * vv.y + tdt2 * ff.y;
        e1[i].z = xx.z + sdt * vv.z + tdt2 * ff.z;
        e1[i].w = xx.w + sdt * vv.w + tdt2 * ff.w;
        e2[i].x = vv.x + sdt * ff.x;
        e2[i].y = vv.y + sdt * ff.y;
        e2[i].z = vv.z + sdt * ff.z;
        e2[i].w = vv.w + sdt * ff.w;
    }

    // ---- WU B-fragments: this wave only ever needs nt=wave -> registers.
    short8 wu[8];
#pragma unroll
    for (int kt = 0; kt < 8; kt++)
        wu[kt] = WUp[(kt * 16 + wave) * 64 + lane];

    __syncthreads();

    // ---- init GEMMs (share B): P = v0@U, FU = f@U ; wave's nt = wave
    floatx4 P  = {0.f, 0.f, 0.f, 0.f};
    floatx4 FU = {0.f, 0.f, 0.f, 0.f};
#pragma unroll 4
    for (int kt = 0; kt < 32; kt++) {
        short8 av = *(const short8*)&va[nl][kt * 32 + quad * 8];
        short8 af = *(const short8*)&fa[nl][kt * 32 + quad * 8];
        short8 bu = Up[(kt * 16 + wave) * 64 + lane];
        P  = __builtin_amdgcn_mfma_f32_16x16x32_bf16(av, bu, P,  0, 0, 0);
        FU = __builtin_amdgcn_mfma_f32_16x16x32_bf16(af, bu, FU, 0, 0, 0);
    }

    // ---- step recurrence in [16][256] space; P fp32 in regs.
    floatx4 A1 = {0.f, 0.f, 0.f, 0.f};   // sum G_j
    floatx4 Q2 = {0.f, 0.f, 0.f, 0.f};   // sum (steps-1-j) G_j
    for (int s = 0; s < steps; s++) {
        short (*pw)[264] = (s & 1) ? q2 : q1;   // double buffer
        float wgt = (float)(steps - 1 - s);
#pragma unroll
        for (int r = 0; r < 4; r++) {
            float g = P[r] * P[r];
            A1[r] += g;
            Q2[r] += wgt * g;
            pw[4 * quad + r][16 * wave + nl] = (short)f2bf(g);
        }
        __syncthreads();
        floatx4 acc = {0.f, 0.f, 0.f, 0.f};
#pragma unroll
        for (int kt = 0; kt < 8; kt++) {
            short8 a = *(const short8*)&pw[nl][kt * 32 + quad * 8];
            acc = __builtin_amdgcn_mfma_f32_16x16x32_bf16(a, wu[kt], acc, 0, 0, 0);
        }
#pragma unroll
        for (int r = 0; r < 4; r++)
            P[r] += DT * (FU[r] - acc[r]);
        // no barrier: next iter writes the OTHER buffer; its barrier
        // guarantees all waves finished this iter's reads first.
    }
    __syncthreads();   // all reads of last pw done before q1/q2 overwrite

    // ---- write Q1 (=A1), Q2 as bf16 A-operands
#pragma unroll
    for (int r = 0; r < 4; r++) {
        q1[4 * quad + r][16 * wave + nl] = (short)f2bf(A1[r]);
        q2[4 * quad + r][16 * wave + nl] = (short)f2bf(Q2[r]);
    }
    __syncthreads();

    // ---- final GEMMs (share B): Y1 = Q1@W, Y2 = Q2@W ; wave nt = 4w..4w+3
    floatx4 y1[4], y2[4];
#pragma unroll
    for (int t = 0; t < 4; t++) {
        y1[t] = (floatx4){0.f, 0.f, 0.f, 0.f};
        y2[t] = (floatx4){0.f, 0.f, 0.f, 0.f};
    }
#pragma unroll 2
    for (int kt = 0; kt < 8; kt++) {
        short8 a1 = *(const short8*)&q1[nl][kt * 32 + quad * 8];
        short8 a2 = *(const short8*)&q2[nl][kt * 32 + quad * 8];
#pragma unroll
        for (int t = 0; t < 4; t++) {
            short8 b = Wp[(kt * 64 + 4 * wave + t) * 64 + lane];
            y1[t] = __builtin_amdgcn_mfma_f32_16x16x32_bf16(a1, b, y1[t], 0, 0, 0);
            y2[t] = __builtin_amdgcn_mfma_f32_16x16x32_bf16(a2, b, y2[t], 0, 0, 0);
        }
    }

    // ---- epilogue: stage GEMM terms (s1 aliases va/fa -- dead since init;
    // post-loop barriers guarantee all waves past those reads), one barrier,
    // fused write from registers: cx = e1 - dt^2*Y2, cv = e2 - dt*Y1.
    float (*s1)[1024] = (float(*)[1024])smem;             // -dt*Y1
    float (*s2)[1024] = (float(*)[1024])(smem + 41472);   // -dt^2*Y2
#pragma unroll
    for (int t = 0; t < 4; t++) {
        int col = 64 * wave + 16 * t + nl;
#pragma unroll
        for (int r = 0; r < 4; r++) {
            int row = 4 * quad + r;
            s1[row][col] = -DT * y1[t][r];
            s2[row][col] = -DT * DT * y2[t][r];
        }
    }
    __syncthreads();

    float4* out4 = (float4*)out;
#pragma unroll
    for (int p = 0; p < 4; p++) {
        int idx = tid + p * 1024;       // 0..4095
        int row = idx >> 8, c4 = idx & 255;
        long gi = (long)(row0 + row) * 256 + c4;
        float4 t1 = *(const float4*)&s1[row][c4 * 4];
        float4 t2 = *(const float4*)&s2[row][c4 * 4];
        float4 ox, ov;
        ox.x = e1[p].x + t2.x;  ox.y = e1[p].y + t2.y;
        ox.z = e1[p].z + t2.z;  ox.w = e1[p].w + t2.w;
        ov.x = e2[p].x + t1.x;  ov.y = e2[p].y + t1.y;
        ov.z = e2[p].z + t1.z;  ov.w = e2[p].w + t1.w;
        out4[gi] = ox;
        out4[(long)BB * 256 + gi] = ov;
    }
}

extern "C" void kernel_launch(void* const* d_in, const int* in_sizes, int n_in,
                              void* d_out, int out_size, void* d_ws, size_t ws_size,
                              hipStream_t stream) {
    const float* x     = (const float*)d_in[0];
    const float* v     = (const float*)d_in[1];
    const float* force = (const float*)d_in[2];
    const float* U     = (const float*)d_in[3];
    const float* W     = (const float*)d_in[4];
    const int*   steps = (const int*)d_in[5];

    short* Up  = (short*)d_ws;                // 262144 shorts = 512 KB
    short* Wp  = Up + 262144;                 // 512 KB
    short* WUp = Wp + 262144;                 // 65536 shorts = 128 KB

    pack_kernel<<<384, 1024, 0, stream>>>(U, W, Up, Wp, WUp);
    euler_kernel<<<256, 1024, 0, stream>>>(x, v, force,
                                           (const short8*)Up, (const short8*)Wp,
                                           (const short8*)WUp,
                                           steps, (float*)d_out);
}